// Round 7
// baseline (383.938 us; speedup 1.0000x reference)
//
#include <hip/hip_runtime.h>
#include <hip/hip_cooperative_groups.h>
#include <math.h>

namespace cg = cooperative_groups;

#define XDIM 47764
#define HDIM 128
#define LDIM 8
#define VTDIM 3620
#define WDIM 32
#define RDIM 8
#define NDIM 512
#define RW 256            // W*R
#define DDIM 48276        // X + RW + 2H
#define FIXED 48148       // X + RW + H (rows of si independent of h_prev_layer)
#define ETDIM 395
#define EPSV 1e-8f

#define CHUNK 768
#define NCHUNK 63         // ceil(48148/768)
#define K1_COMPUTE (32 * NCHUNK)   // 2016
#define K1_COPYB 128               // wrec copy blocks

// ws layout (float offsets)
#define OFF_PARTIAL 0          // 32*63*128 = 258048
#define OFF_FIXED   258048     // 32*128
#define OFF_WREC    262144     // 32*128*128 = 524288
#define OFF_FLAT    786432     // 1024
#define OFF_ERAW    787456     // 512
#define OFF_WW      787968     // 512
#define OFF_MEMNEW  788480     // 16384
#define OFF_CR      804864     // 4096
#define OFF_RM      808960     // 32
#define OFF_FW      808992     // 4096
#define OFF_BW      813088     // 4096
#define OFF_RV      817184     // 256

typedef float f4 __attribute__((ext_vector_type(4)));

__device__ __forceinline__ f4 ntload4(const float* p) {
    return __builtin_nontemporal_load((const f4*)p);
}

__device__ inline float sigm(float x) { return 1.f / (1.f + expf(-x)); }
__device__ inline float log_sigmoid(float x) {
    return (x >= 0.f) ? -log1pf(expf(-x)) : (x - log1pf(expf(x)));
}

// ---------------- K1: gate pre-activations (nontemporal) + weight compaction
__global__ __launch_bounds__(256) void k1_partial(
    const float* __restrict__ x_in, const float* __restrict__ lrv,
    const float* __restrict__ hprev,
    const float* __restrict__ Wi, const float* __restrict__ Wf,
    const float* __restrict__ Wo, const float* __restrict__ Ws,
    float* __restrict__ ws)
{
    const int bid = blockIdx.x;
    const int t   = threadIdx.x;

    if (bid >= K1_COMPUTE) {
        // compaction: W*[l][FIXED+j][h] -> wrec[combo][j][h]
        int cb = bid - K1_COMPUTE;
        #pragma unroll
        for (int r = 0; r < 4; ++r) {
            int idx4  = cb * 1024 + r * 256 + t;
            int flat  = idx4 << 2;
            int combo = flat >> 14;
            int rem   = flat & 16383;
            int j = rem >> 7, h = rem & 127;
            int g = combo >> 3, l = combo & 7;
            const float* Wg = (g == 0) ? Wi : (g == 1) ? Wf : (g == 2) ? Wo : Ws;
            float4 v = *reinterpret_cast<const float4*>(
                Wg + ((size_t)l * DDIM + FIXED + j) * HDIM + h);
            *reinterpret_cast<float4*>(ws + OFF_WREC + flat) = v;
        }
        return;
    }

    const int combo = bid / NCHUNK;
    const int chunk = bid % NCHUNK;
    const int g = combo >> 3, l = combo & 7;
    const float* __restrict__ Wg = (g == 0) ? Wi : (g == 1) ? Wf : (g == 2) ? Wo : Ws;
    const int d0 = chunk * CHUNK;

    __shared__ float s_lds[CHUNK];
    for (int i = t; i < CHUNK; i += 256) {
        int d = d0 + i;
        float v = 0.f;
        if (d < XDIM)            v = x_in[d];
        else if (d < XDIM + RW)  v = lrv[d - XDIM];
        else if (d < FIXED)      v = hprev[l * HDIM + (d - XDIM - RW)];
        s_lds[i] = v;
    }
    __syncthreads();

    const int c4 = t & 15;    // float4 column -> cols c4 and c4+16
    const int p  = t >> 4;    // row slice 0..15, each 48 contiguous rows
    const int r0 = p * 48;
    const float* wp = Wg + ((size_t)l * DDIM + d0 + r0) * HDIM + (c4 << 2);

    f4 a = {0.f, 0.f, 0.f, 0.f};
    f4 b = {0.f, 0.f, 0.f, 0.f};

    if (chunk != NCHUNK - 1) {
        #pragma unroll 4
        for (int i = 0; i < 48; ++i) {
            float s = s_lds[r0 + i];
            const f4 w0 = ntload4(wp);
            const f4 w1 = ntload4(wp + 64);
            wp += HDIM;
            a += s * w0;
            b += s * w1;
        }
    } else {
        for (int i = 0; i < 48; ++i) {
            if (d0 + r0 + i >= FIXED) break;
            float s = s_lds[r0 + i];
            const f4 w0 = ntload4(wp);
            const f4 w1 = ntload4(wp + 64);
            wp += HDIM;
            a += s * w0;
            b += s * w1;
        }
    }

    __shared__ f4 red[16][32];
    red[p][c4]      = a;
    red[p][c4 + 16] = b;
    __syncthreads();
    if (t < 32) {
        f4 s = red[0][t];
        #pragma unroll
        for (int q = 1; q < 16; ++q) s += red[q][t];
        *reinterpret_cast<f4*>(ws + OFF_PARTIAL +
            ((size_t)(combo * NCHUNK + chunk)) * HDIM + (t << 2)) = s;
    }
}

// =========== tail_fused: everything after k1, one cooperative launch ========
__global__ __launch_bounds__(512) void tail_fused(
    const float* __restrict__ bi, const float* __restrict__ bf,
    const float* __restrict__ bo, const float* __restrict__ bs,
    const float* __restrict__ old_st,
    const float* __restrict__ Wy, const float* __restrict__ We,
    const float* __restrict__ Wr,
    const float* __restrict__ memory, const float* __restrict__ lrw,
    const float* __restrict__ lu, const float* __restrict__ lww,
    const float* __restrict__ linkage, const float* __restrict__ prec,
    float* __restrict__ ws, float* __restrict__ out)
{
    cg::grid_group grid = cg::this_grid();
    const int blk = blockIdx.x, t = threadIdx.x;
    const int lane = t & 63, wid = t >> 6;

    __shared__ float smem[6272];   // ~25 KB, phase-multiplexed

    // ---- P0: reduce 63 chunk-partials + bias -> fixed[32][128] (blocks 0..31)
    if (blk < 32) {
        const int seg = t >> 7, h = t & 127;
        float acc = 0.f;
        for (int c = seg; c < NCHUNK; c += 4)
            acc += ws[OFF_PARTIAL + (size_t)(blk * NCHUNK + c) * HDIM + h];
        smem[seg * 128 + h] = acc;
        __syncthreads();
        if (t < 128) {
            int g = blk >> 3, l = blk & 7;
            const float* bg = (g == 0) ? bi : (g == 1) ? bf : (g == 2) ? bo : bs;
            ws[OFF_FIXED + blk * HDIM + t] =
                smem[t] + smem[128 + t] + smem[256 + t] + smem[384 + t]
                + bg[l * HDIM + t];
        }
    }
    grid.sync();

    // ---- P1: sequential layer chain (block 0)
    if (blk == 0) {
        float* hp = smem;           // 128
        float* gl = smem + 128;     // 4*128
        const int g = t >> 7, h = t & 127;
        float fx[LDIM];
        #pragma unroll
        for (int l = 0; l < LDIM; ++l)
            fx[l] = ws[OFF_FIXED + (g * 8 + l) * HDIM + h];
        if (t < 128) hp[t] = 0.f;
        __syncthreads();
        for (int l = 0; l < LDIM; ++l) {
            const float* wr = ws + OFF_WREC + (size_t)(g * 8 + l) * 16384 + h;
            float acc = fx[l];
            #pragma unroll 16
            for (int j = 0; j < 128; ++j) acc += hp[j] * wr[j * 128];
            gl[g * 128 + h] = acc;
            __syncthreads();
            if (t < 128) {
                float ig = sigm(gl[t]);
                float fg = sigm(gl[128 + t]);
                float og = sigm(gl[256 + t]);
                float ss = tanhf(gl[384 + t]);
                float st = fg * old_st[l * HDIM + t] + ig * ss;
                float hn = og * tanhf(st);
                hp[t] = hn;
                ws[OFF_FLAT + l * HDIM + t] = hn;
            }
            __syncthreads();
        }
    }
    grid.sync();

    // ---- P2: flat@Wy -> out (blocks 0..226), flat@We -> eraw (227..234)
    if (blk < 227) {
        float* flat_s = smem;          // 1024
        float* pr     = smem + 1024;   // 32*16
        flat_s[t]       = ws[OFF_FLAT + t];
        flat_s[512 + t] = ws[OFF_FLAT + 512 + t];
        __syncthreads();
        const int ks = t >> 4, v16 = t & 15;
        const int v = blk * 16 + v16;
        float acc = 0.f;
        if (v < VTDIM) {
            const float* Wp = Wy + (size_t)(ks * 32) * VTDIM + v;
            #pragma unroll 8
            for (int k = 0; k < 32; ++k)
                acc += flat_s[ks * 32 + k] * Wp[(size_t)k * VTDIM];
        }
        pr[ks * 16 + v16] = acc;
        __syncthreads();
        if (t < 16) {
            float s = 0.f;
            #pragma unroll
            for (int q = 0; q < 32; ++q) s += pr[q * 16 + t];
            int vv = blk * 16 + t;
            if (vv < VTDIM) out[vv] = s;
        }
    } else if (blk < 235) {
        float* flat_s = smem;
        float* pr     = smem + 1024;   // 8*64
        flat_s[t]       = ws[OFF_FLAT + t];
        flat_s[512 + t] = ws[OFF_FLAT + 512 + t];
        __syncthreads();
        const int ks = t >> 6, e64 = t & 63;
        const int e = (blk - 227) * 64 + e64;
        float acc = 0.f;
        if (e < ETDIM) {
            const float* Wp = We + (size_t)(ks * 128) * ETDIM + e;
            #pragma unroll 8
            for (int k = 0; k < 128; ++k)
                acc += flat_s[ks * 128 + k] * Wp[(size_t)k * ETDIM];
        }
        pr[ks * 64 + e64] = acc;
        __syncthreads();
        if (t < 64) {
            float s = 0.f;
            #pragma unroll
            for (int q = 0; q < 8; ++q) s += pr[q * 64 + t];
            int ee = (blk - 227) * 64 + t;
            if (ee < ETDIM) ws[OFF_ERAW + ee] = s;
        }
    }
    grid.sync();

    // ---- P3: E unpack + usage/alloc + write/memory/cr (block 0)
    if (blk == 0) {
        float* Es   = smem;          // 400 (pad 416)
        float* rk   = smem + 416;    // 256
        float* wk   = smem + 672;    // 32
        float* er   = smem + 704;    // 32
        float* wvv  = smem + 736;    // 32
        float* fgs  = smem + 768;    // 8
        float* rss  = smem + 776;    // 8
        float* rm   = smem + 784;    // 24
        float* scal = smem + 808;    // 4
        float* u_s  = smem + 816;    // 512
        float* wred = smem + 1328;   // 8
        float* wred8= smem + 1336;   // 64
        float* srk  = smem + 1400;   // 8

        if (t < ETDIM) Es[t] = ws[OFF_ERAW + t];
        __syncthreads();

        if (t < 256)                 rk[t] = Es[t];
        if (t >= 256 && t < 264)     rss[t - 256] = 1.f - log_sigmoid(Es[t]);
        if (t >= 264 && t < 296)     wk[t - 264] = Es[t];
        if (t == 296)                scal[0] = 1.f - log_sigmoid(Es[296]);
        if (t >= 297 && t < 329)     er[t - 297] = sigm(Es[t]);
        if (t >= 329 && t < 361)     wvv[t - 329] = Es[t];
        if (t >= 361 && t < 369)     fgs[t - 361] = sigm(Es[t]);
        if (t == 369)                scal[1] = sigm(Es[369]);
        if (t == 370)                scal[2] = sigm(Es[370]);
        if (t >= 384 && t < 392) {
            int r = t - 384;
            float a = Es[371 + 3*r], b = Es[372 + 3*r], c = Es[373 + 3*r];
            float mx = fmaxf(a, fmaxf(b, c));
            float ea = expf(a - mx), eb = expf(b - mx), ec = expf(c - mx);
            float s = ea + eb + ec;
            rm[3*r] = ea / s; rm[3*r + 1] = eb / s; rm[3*r + 2] = ec / s;
        }
        __syncthreads();

        float psi = 1.f;
        #pragma unroll
        for (int r = 0; r < 8; ++r) psi *= 1.f - fgs[r] * lrw[t * 8 + r];
        float ua = lu[t], ub = lww[t];
        float u_t = (ua + ub - ua * ub) * psi;
        u_s[t] = u_t;
        __syncthreads();

        float prod = 1.f;
        for (int j = 0; j < 512; ++j) {
            float uj = u_s[j];
            bool before = (uj < u_t) || (uj == u_t && j < t);
            prod *= before ? uj : 1.f;
        }
        float alloc_t = (1.f - u_t) * prod;

        float s2 = 0.f;
        #pragma unroll
        for (int w = 0; w < 32; ++w) s2 += wk[w] * wk[w];
        float wkinv = 1.f / fmaxf(sqrtf(s2), EPSV);

        float mrow[32];
        float dotv = 0.f, nn = 0.f;
        #pragma unroll
        for (int w = 0; w < 32; ++w) {
            float m = memory[t * 32 + w];
            mrow[w] = m; dotv += m * wk[w]; nn += m * m;
        }
        float score = scal[0] * wkinv * dotv / fmaxf(sqrtf(nn), EPSV);
        float v = score;
        #pragma unroll
        for (int o = 32; o > 0; o >>= 1) v = fmaxf(v, __shfl_xor(v, o));
        if (lane == 0) wred[wid] = v;
        __syncthreads();
        float mx = wred[0];
        #pragma unroll
        for (int qq = 1; qq < 8; ++qq) mx = fmaxf(mx, wred[qq]);
        __syncthreads();
        float e = expf(score - mx);
        v = e;
        #pragma unroll
        for (int o = 32; o > 0; o >>= 1) v += __shfl_xor(v, o);
        if (lane == 0) wred[wid] = v;
        __syncthreads();
        float ssum = 0.f;
        #pragma unroll
        for (int qq = 0; qq < 8; ++qq) ssum += wred[qq];
        float cwv = e / ssum;

        float wwn = scal[2] * (scal[1] * alloc_t + (1.f - scal[1]) * cwv);
        ws[OFF_WW + t] = wwn;

        float nn2 = 0.f;
        #pragma unroll
        for (int w = 0; w < 32; ++w) {
            float mn = mrow[w] * (1.f - wwn * er[w]) + wwn * wvv[w];
            mrow[w] = mn; nn2 += mn * mn;
            ws[OFF_MEMNEW + t * 32 + w] = mn;
        }
        float inv2 = 1.f / fmaxf(sqrtf(nn2), EPSV);

        if (t < 8) {
            float s3 = 0.f;
            #pragma unroll
            for (int w = 0; w < 32; ++w) { float x = rk[w * 8 + t]; s3 += x * x; }
            srk[t] = rss[t] / fmaxf(sqrtf(s3), EPSV);
        }
        __syncthreads();

        float sc[8];
        #pragma unroll
        for (int r = 0; r < 8; ++r) {
            float d2 = 0.f;
            #pragma unroll
            for (int w = 0; w < 32; ++w) d2 += mrow[w] * rk[w * 8 + r];
            sc[r] = srk[r] * inv2 * d2;
        }
        #pragma unroll
        for (int r = 0; r < 8; ++r) {
            float x = sc[r];
            #pragma unroll
            for (int o = 32; o > 0; o >>= 1) x = fmaxf(x, __shfl_xor(x, o));
            if (lane == 0) wred8[wid * 8 + r] = x;
        }
        __syncthreads();
        float mxr[8];
        #pragma unroll
        for (int r = 0; r < 8; ++r) {
            float m = wred8[r];
            #pragma unroll
            for (int qq = 1; qq < 8; ++qq) m = fmaxf(m, wred8[qq * 8 + r]);
            mxr[r] = m;
        }
        __syncthreads();
        float ex[8];
        #pragma unroll
        for (int r = 0; r < 8; ++r) {
            ex[r] = expf(sc[r] - mxr[r]);
            float x = ex[r];
            #pragma unroll
            for (int o = 32; o > 0; o >>= 1) x += __shfl_xor(x, o);
            if (lane == 0) wred8[wid * 8 + r] = x;
        }
        __syncthreads();
        #pragma unroll
        for (int r = 0; r < 8; ++r) {
            float sm = 0.f;
            #pragma unroll
            for (int qq = 0; qq < 8; ++qq) sm += wred8[qq * 8 + r];
            ws[OFF_CR + t * 8 + r] = ex[r] / sm;
        }
        if (t < 24) ws[OFF_RM + t] = rm[t];
    }
    grid.sync();

    // ---- P4: linkage fw/bw — 2 fw rows + 2 bw rows per block
    {
        float* lrw_s  = smem;          // 512*9 padded = 4608
        float* ww_s   = smem + 4608;   // 512
        float* rowred = smem + 5120;   // 8*8
        for (int i = t; i < 4096; i += 512)
            lrw_s[(i >> 3) * 9 + (i & 7)] = lrw[i];
        ww_s[t] = ws[OFF_WW + t];
        __syncthreads();

        const float pt = prec[t];
        const float wwt = ww_s[t];
        float la[8];
        #pragma unroll
        for (int r = 0; r < 8; ++r) la[r] = lrw_s[t * 9 + r];

        #pragma unroll
        for (int pass = 0; pass < 4; ++pass) {
            const int i = blk * 2 + (pass & 1);
            float lm;
            if (pass < 2) {   // fw: Lm[i][t]
                float lj = linkage[(size_t)i * 512 + t];
                lm = (t == i) ? 0.f : (1.f - ww_s[i] - wwt) * lj + ww_s[i] * pt;
            } else {          // bw: Lm[t][i]
                float lj = linkage[(size_t)t * 512 + i];
                lm = (t == i) ? 0.f : (1.f - wwt - ww_s[i]) * lj + wwt * prec[i];
            }
            #pragma unroll
            for (int r = 0; r < 8; ++r) {
                float v = lm * la[r];
                #pragma unroll
                for (int o = 32; o > 0; o >>= 1) v += __shfl_xor(v, o);
                if (lane == 0) rowred[wid * 8 + r] = v;
            }
            __syncthreads();
            if (t < 8) {
                float s = 0.f;
                #pragma unroll
                for (int w = 0; w < 8; ++w) s += rowred[w * 8 + t];
                ws[((pass < 2) ? OFF_FW : OFF_BW) + i * 8 + t] = s;
            }
            __syncthreads();
        }
    }
    grid.sync();

    // ---- P5: rw -> rv (block 0)
    if (blk == 0) {
        float* rw_s = smem;          // 4096
        float* rred = smem + 4096;   // 8*32*8 = 2048
        float* rm_s = smem + 6144;   // 24
        if (t < 24) rm_s[t] = ws[OFF_RM + t];
        __syncthreads();
        for (int idx = t; idx < 4096; idx += 512) {
            int r = idx & 7;
            rw_s[idx] = ws[OFF_BW + idx] * rm_s[r * 3]
                      + ws[OFF_CR + idx] * rm_s[r * 3 + 1]
                      + ws[OFF_FW + idx] * rm_s[r * 3 + 2];
        }
        __syncthreads();

        const int g = t >> 5, w = t & 31;    // 16 groups x 32 n
        float acc[8] = {0,0,0,0,0,0,0,0};
        for (int n = g * 32; n < g * 32 + 32; ++n) {
            float m = ws[OFF_MEMNEW + n * 32 + w];
            #pragma unroll
            for (int r = 0; r < 8; ++r) acc[r] += m * rw_s[n * 8 + r];
        }
        #pragma unroll
        for (int r = 0; r < 8; ++r) {
            float v = acc[r] + __shfl_xor(acc[r], 32);   // combine group pair
            if (lane < 32) rred[(wid * 32 + w) * 8 + r] = v;
        }
        __syncthreads();
        if (t < 256) {
            int w2 = t >> 3, r2 = t & 7;
            float s = 0.f;
            #pragma unroll
            for (int qq = 0; qq < 8; ++qq) s += rred[(qq * 32 + w2) * 8 + r2];
            ws[OFF_RV + w2 * 8 + r2] = s;
        }
    }
    grid.sync();

    // ---- P6: out += rv @ Wr (blocks 0..113)
    if (blk < 114) {
        float* rv_s = smem;          // 256
        float* pr   = smem + 256;    // 16*32
        if (t < 256) rv_s[t] = ws[OFF_RV + t];
        __syncthreads();
        const int ks = t >> 5, v32 = t & 31;
        const int v = blk * 32 + v32;
        float acc = 0.f;
        if (v < VTDIM) {
            const float* Wp = Wr + (size_t)(ks * 16) * VTDIM + v;
            #pragma unroll
            for (int k = 0; k < 16; ++k) acc += rv_s[ks * 16 + k] * Wp[(size_t)k * VTDIM];
        }
        pr[ks * 32 + v32] = acc;
        __syncthreads();
        if (t < 32) {
            int vv = blk * 32 + t;
            if (vv < VTDIM) {
                float s = 0.f;
                #pragma unroll
                for (int q = 0; q < 16; ++q) s += pr[q * 32 + t];
                atomicAdd(&out[vv], s);
            }
        }
    }
}

extern "C" void kernel_launch(void* const* d_in, const int* in_sizes, int n_in,
                              void* d_out, int out_size, void* d_ws, size_t ws_size,
                              hipStream_t stream)
{
    const float* x_in   = (const float*)d_in[0];
    const float* Wi     = (const float*)d_in[1];
    const float* bi     = (const float*)d_in[2];
    const float* Wf     = (const float*)d_in[3];
    const float* bf     = (const float*)d_in[4];
    const float* Wo     = (const float*)d_in[5];
    const float* bo     = (const float*)d_in[6];
    const float* Wss    = (const float*)d_in[7];
    const float* bs     = (const float*)d_in[8];
    const float* Wy     = (const float*)d_in[9];
    const float* We     = (const float*)d_in[10];
    const float* Wr     = (const float*)d_in[11];
    const float* memory = (const float*)d_in[12];
    const float* lrv    = (const float*)d_in[13];
    const float* hprev  = (const float*)d_in[14];
    const float* old_st = (const float*)d_in[15];
    const float* prec   = (const float*)d_in[16];
    const float* linkage= (const float*)d_in[17];
    const float* lrw    = (const float*)d_in[18];
    const float* lu     = (const float*)d_in[19];
    const float* lww    = (const float*)d_in[20];
    float* out = (float*)d_out;
    float* ws  = (float*)d_ws;

    k1_partial<<<K1_COMPUTE + K1_COPYB, 256, 0, stream>>>(
        x_in, lrv, hprev, Wi, Wf, Wo, Wss, ws);

    void* args[] = {
        (void*)&bi, (void*)&bf, (void*)&bo, (void*)&bs, (void*)&old_st,
        (void*)&Wy, (void*)&We, (void*)&Wr,
        (void*)&memory, (void*)&lrw, (void*)&lu, (void*)&lww,
        (void*)&linkage, (void*)&prec, (void*)&ws, (void*)&out
    };
    hipLaunchCooperativeKernel((void*)tail_fused, dim3(256), dim3(512),
                               args, 0, stream);
}